// Round 5
// baseline (1360.169 us; speedup 1.0000x reference)
//
#include <hip/hip_runtime.h>
#include <math.h>

// Problem constants
#define BB 512
#define SS 64
#define DD 128
#define FF 256   // 2D
#define NSYM 128
#define STK 16
#define NDEPTH 8

typedef _Float16 half_t;
typedef __attribute__((ext_vector_type(4))) _Float16 half4;
typedef __attribute__((ext_vector_type(8))) _Float16 half8;
typedef __attribute__((ext_vector_type(4))) float f32x4;

// Workspace offsets (in floats)
#define Z_OFF      0ull                    // B*S*F      = 8388608
#define QKV_OFF    8388608ull              // WT32 + GT/WvT split planes
#define MEM_OFF    33554432ull             // B*16*F     = 2097152
#define MEMQKV_OFF 35651584ull             // B*16*768   = 6291456
#define PTR_OFF    41943040ull             // B*16       = 8192
#define ZF1_OFF    41951232ull             // B*256      = 131072
#define ZF2_OFF    42082304ull             // B*256      = 131072
#define READ_OFF   42213376ull             // B*256      = 131072
#define PROBS_OFF  42344448ull             // B*128      = 65536
#define DELTA_OFF  42409984ull             // B*256      = 131072 (read + quant)
#define HALT_OFF   42541056ull             // B          = 512
#define PVAL_OFF   42541568ull             // B          = 512
#define WACT_OFF   42542080ull             // B          = 512
#define MAGP_OFF   42542592ull             // B*2        = 1024
#define MQKV_OFF   42740224ull             // 196608 floats (MTh+MTl fp16)
#define CB2_OFF    42936832ull             // 128

// ---------------------------------------------------------------------------
// Combined transposed weight, fp32: WT32[h][c][e] = W_h[e][c], h in {q,k,v}
__global__ void k_buildwt32(const float* __restrict__ wr, const float* __restrict__ wi,
                            float* __restrict__ WT32) {
    int idx = blockIdx.x * 256 + threadIdx.x;   // 196608 total, grid=768
    if (idx >= 768 * 256) return;
    int col = idx >> 8;     // 0..767 = h*256 + c
    int e   = idx & 255;
    int h   = col >> 8;
    int c   = col & 255;
    const float* Wr = wr + h * DD * DD;
    const float* Wi = wi + h * DD * DD;
    float v;
    if (c < DD) {
        v = (e < DD) ? Wr[c * DD + e] : -Wi[c * DD + (e - DD)];
    } else {
        int j = c - DD;
        v = (e < DD) ? Wi[j * DD + e] : Wr[j * DD + (e - DD)];
    }
    WT32[idx] = v;
}

// GT[n][e] = G[e][n] = sum_c Wq[e][c]*Wk[n][c], split to fp16 h/l (unscaled).
__global__ __launch_bounds__(256) void k_buildG(const float* __restrict__ WT32,
                                                half_t* __restrict__ GTh,
                                                half_t* __restrict__ GTl) {
    __shared__ float kcol[256];
    int n = blockIdx.x;       // 0..255
    int e = threadIdx.x;      // 0..255
    kcol[e] = WT32[65536 + e * 256 + n];   // Wk[n][c=e]
    __syncthreads();
    float s = 0.f;
    for (int c = 0; c < 256; ++c) s += kcol[c] * WT32[c * 256 + e];  // Wq[e][c]
    half_t h = (half_t)s;
    GTh[n * 256 + e] = h;
    GTl[n * 256 + e] = (half_t)(s - (float)h);
}

__global__ void k_splitWv(const float* __restrict__ WT32,
                          half_t* __restrict__ WvTh, half_t* __restrict__ WvTl) {
    int idx = blockIdx.x * 256 + threadIdx.x;   // 65536, grid 256
    float v = WT32[131072 + idx];   // WvT[n][e] = Wv[e][n]
    half_t h = (half_t)v;
    WvTh[idx] = h;
    WvTl[idx] = (half_t)(v - (float)h);
}

// Memory-path combined transposed split weights.
__global__ void k_buildwt(const float* __restrict__ wr, const float* __restrict__ wi,
                          half_t* __restrict__ WTh, half_t* __restrict__ WTl) {
    int idx = blockIdx.x * 256 + threadIdx.x;   // 196608 total, grid=768
    if (idx >= 768 * 256) return;
    int col = idx >> 8;
    int e   = idx & 255;
    int h   = col >> 8;
    int c   = col & 255;
    const float* Wr = wr + h * DD * DD;
    const float* Wi = wi + h * DD * DD;
    float v;
    if (c < DD) {
        v = (e < DD) ? Wr[c * DD + e] : -Wi[c * DD + (e - DD)];
    } else {
        int j = c - DD;
        v = (e < DD) ? Wi[j * DD + e] : Wr[j * DD + (e - DD)];
    }
    half_t hh = (half_t)v;
    WTh[idx] = hh;
    WTl[idx] = (half_t)(v - (float)hh);
}

__global__ void k_cb2(const float* __restrict__ cb, float* __restrict__ cb2) {
    int n = threadIdx.x;   // 128 threads
    float s = 0.f;
    for (int c = 0; c < FF; ++c) { float v = cb[n * FF + c]; s += v * v; }
    cb2[n] = s;
}

__global__ __launch_bounds__(256) void k_init(const float* __restrict__ zr_in,
                                              const float* __restrict__ zi_in,
                                              float* __restrict__ z, float* __restrict__ memv,
                                              float* __restrict__ ptrv, float* __restrict__ probs,
                                              float* __restrict__ halt, float* __restrict__ acc,
                                              float* __restrict__ delta, float* __restrict__ wact) {
    size_t idx = (size_t)blockIdx.x * 256 + threadIdx.x;  // grid 32768 -> 8388608
    int c = (int)(idx & 255);
    size_t bs = idx >> 8;
    z[idx] = (c < DD) ? zr_in[bs * DD + c] : zi_in[bs * DD + (c - DD)];
    acc[idx] = 0.f;
    if (idx < 2097152) memv[idx] = 0.f;
    if (idx < 131072) delta[idx] = 0.f;
    if (idx < 8192)  ptrv[idx] = ((idx & 15) == 0) ? 1.f : 0.f;
    if (idx < 65536) probs[idx] = 0.f;
    if (idx < 512)   { halt[idx] = 0.f; wact[idx] = 0.f; }
}

// ---------------------------------------------------------------------------
// LDS swizzle helpers (byte offsets)
__device__ __forceinline__ int zswz(int row, int colhalf) {   // Z plane: 64x256 halfs
    return ((row << 9) + (colhalf << 1)) ^ ((row & 7) << 4);
}
__device__ __forceinline__ int pswz(int row, int colhalf) {   // P plane: 64x64 halfs
    return ((row << 7) + (colhalf << 1)) ^ ((row & 7) << 4);
}

// Build split-fp16 B-fragment from distributed f32 accum tiles via cross-lane shfl.
// ve/vo: even/odd source tile (this lane's registers). Value for (lane, jj):
//   src tile = (lane&32)?vo:ve, reg r = jj&3, srcLane = (lane&15)|((lane&16)<<1)|((jj&4)<<2)
__device__ __forceinline__ void xfrag(const f32x4 ve, const f32x4 vo, int srcA,
                                      int lane, float sc, half8& h8, half8& l8) {
#pragma unroll
    for (int jj = 0; jj < 8; ++jj) {
        int src = srcA + ((jj & 4) << 2);
        float a  = __shfl(ve[jj & 3], src, 64);
        float bb = __shfl(vo[jj & 3], src, 64);
        float v = ((lane & 32) ? bb : a) * sc;
        half_t h = (half_t)v;
        h8[jj] = h;
        l8[jj] = (half_t)(v - (float)h);
    }
}

// ---------------------------------------------------------------------------
// Fused attention step, 2-blocks/CU design. One block (4 waves) per batch.
//   x0 = z + 0.1*delta_prev;  acc += wact_prev*x0
//   TT = G^T x0^T per-wave (regs);  S^T = x0 @ TT (B via shfl);  softmax -> P (LDS)
//   V = x0 @ Wv per-wave c-band (regs);  O = P @ V^T (B via shfl)
//   z_out = O + 0.1*x0;  zf1 = colmean (per-wave, direct)
__global__ __launch_bounds__(256, 2) void k_attn2(
        float* __restrict__ z,
        const half_t* __restrict__ GTh, const half_t* __restrict__ GTl,
        const half_t* __restrict__ WvTh, const half_t* __restrict__ WvTl,
        const float* __restrict__ delta, const float* __restrict__ wact,
        float* __restrict__ acc, float* __restrict__ zf1) {
    __shared__ half_t Zh[16384];   // 32 KB
    __shared__ half_t Zl[16384];   // 32 KB
    __shared__ half_t Ph[4096];    // 8 KB
    __shared__ half_t Pl[4096];    // 8 KB   -> total 80 KB exactly

    int b = blockIdx.x, tid = threadIdx.x;
    int w = tid >> 6, lane = tid & 63;
    int l15 = lane & 15, lq = lane >> 4;
    int srcA = (lane & 15) | ((lane & 16) << 1);
    float* zb = z + (size_t)b * (SS * FF);
    float* accb = acc + (size_t)b * (SS * FF);
    char* Zhc = (char*)Zh; char* Zlc = (char*)Zl;
    char* Phc = (char*)Ph; char* Plc = (char*)Pl;

    // ---- phase 0: x0 = z + 0.1*delta; deferred acc; split to LDS
    float wa = wact[b];
    f32x4 dv = *(const f32x4*)(delta + b * FF + lane * 4);
    bool doacc = (wa != 0.0f);
#pragma unroll
    for (int it = 0; it < 16; ++it) {
        int i = w * 16 + it;
        f32x4 zv = *(const f32x4*)(zb + (size_t)i * FF + lane * 4);
        f32x4 x0;
#pragma unroll
        for (int jj = 0; jj < 4; ++jj) x0[jj] = zv[jj] + 0.1f * dv[jj];
        if (doacc) {
            f32x4 av = *(const f32x4*)(accb + (size_t)i * FF + lane * 4);
#pragma unroll
            for (int jj = 0; jj < 4; ++jj) av[jj] += wa * x0[jj];
            *(f32x4*)(accb + (size_t)i * FF + lane * 4) = av;
        }
        half4 h4, l4;
#pragma unroll
        for (int jj = 0; jj < 4; ++jj) {
            half_t h = (half_t)x0[jj];
            h4[jj] = h; l4[jj] = (half_t)(x0[jj] - (float)h);
        }
        int zo = zswz(i, lane * 4);
        *(half4*)(Zhc + zo) = h4;
        *(half4*)(Zlc + zo) = l4;
    }
    __syncthreads();   // sync #1: Z staged

    // ---- phase TT: TT[k][i for w's 16 queries] in regs.  A=GT rows k, B=x0 row (w*16+l15)
    f32x4 tt[16];
#pragma unroll
    for (int kt2 = 0; kt2 < 16; ++kt2) tt[kt2] = (f32x4){0.f, 0.f, 0.f, 0.f};
    for (int kt = 0; kt < 8; ++kt) {
        int kc = kt * 32 + lq * 8;
        int zo = zswz(w * 16 + l15, kc);
        half8 bh = *(const half8*)(Zhc + zo);
        half8 bl = *(const half8*)(Zlc + zo);
#pragma unroll
        for (int ktile = 0; ktile < 16; ++ktile) {
            size_t go = (size_t)(ktile * 16 + l15) * 256 + kc;
            half8 gh = *(const half8*)(GTh + go);
            half8 gl = *(const half8*)(GTl + go);
            tt[ktile] = __builtin_amdgcn_mfma_f32_16x16x32_f16(gh, bh, tt[ktile], 0, 0, 0);
            tt[ktile] = __builtin_amdgcn_mfma_f32_16x16x32_f16(gh, bl, tt[ktile], 0, 0, 0);
            tt[ktile] = __builtin_amdgcn_mfma_f32_16x16x32_f16(gl, bh, tt[ktile], 0, 0, 0);
        }
    }

    // ---- phase S: S^T[j][w's queries]; A = x0 rows j (LDS), B = TT via shfl (scale folded)
    {
        const float scale = 0.08838834764831845f;
        f32x4 sac[4];
#pragma unroll
        for (int jt = 0; jt < 4; ++jt) sac[jt] = (f32x4){0.f, 0.f, 0.f, 0.f};
        for (int kt = 0; kt < 8; ++kt) {
            half8 bh, bl;
            xfrag(tt[kt * 2], tt[kt * 2 + 1], srcA, lane, scale, bh, bl);
            int kc = kt * 32 + lq * 8;
#pragma unroll
            for (int jt = 0; jt < 4; ++jt) {
                int zo = zswz(jt * 16 + l15, kc);
                half8 ah = *(const half8*)(Zhc + zo);
                half8 al = *(const half8*)(Zlc + zo);
                sac[jt] = __builtin_amdgcn_mfma_f32_16x16x32_f16(ah, bh, sac[jt], 0, 0, 0);
                sac[jt] = __builtin_amdgcn_mfma_f32_16x16x32_f16(ah, bl, sac[jt], 0, 0, 0);
                sac[jt] = __builtin_amdgcn_mfma_f32_16x16x32_f16(al, bh, sac[jt], 0, 0, 0);
            }
        }
        // softmax over j for query i = w*16+l15 (values spread over lq group)
        float sv[4][4];
        float mx = -1e30f;
#pragma unroll
        for (int jt = 0; jt < 4; ++jt)
#pragma unroll
            for (int r = 0; r < 4; ++r) { sv[jt][r] = sac[jt][r]; mx = fmaxf(mx, sv[jt][r]); }
        mx = fmaxf(mx, __shfl_xor(mx, 16));
        mx = fmaxf(mx, __shfl_xor(mx, 32));
        float ssum = 0.f;
#pragma unroll
        for (int jt = 0; jt < 4; ++jt)
#pragma unroll
            for (int r = 0; r < 4; ++r) { float e = expf(sv[jt][r] - mx); sv[jt][r] = e; ssum += e; }
        ssum += __shfl_xor(ssum, 16);
        ssum += __shfl_xor(ssum, 32);
        float inv = 1.f / ssum;
#pragma unroll
        for (int jt = 0; jt < 4; ++jt) {
            half4 h4, l4;
#pragma unroll
            for (int r = 0; r < 4; ++r) {
                float pv = sv[jt][r] * inv;
                half_t hh = (half_t)pv;
                h4[r] = hh;
                l4[r] = (half_t)(pv - (float)hh);
            }
            int po = pswz(w * 16 + l15, jt * 16 + lq * 4);
            *(half4*)(Phc + po) = h4;
            *(half4*)(Plc + po) = l4;
        }
    }

    // ---- phase V: V[j][w's 64-col band] in regs. A = x0 rows (LDS), B = WvT band
    f32x4 vv[4][4];
#pragma unroll
    for (int mt = 0; mt < 4; ++mt)
#pragma unroll
        for (int nt = 0; nt < 4; ++nt) vv[mt][nt] = (f32x4){0.f, 0.f, 0.f, 0.f};
    for (int kt = 0; kt < 8; ++kt) {
        int kc = kt * 32 + lq * 8;
        half8 ah[4], al[4];
#pragma unroll
        for (int mt = 0; mt < 4; ++mt) {
            int zo = zswz(mt * 16 + l15, kc);
            ah[mt] = *(const half8*)(Zhc + zo);
            al[mt] = *(const half8*)(Zlc + zo);
        }
#pragma unroll
        for (int nt = 0; nt < 4; ++nt) {
            size_t go = (size_t)(w * 64 + nt * 16 + l15) * 256 + kc;
            half8 gh = *(const half8*)(WvTh + go);
            half8 gl = *(const half8*)(WvTl + go);
#pragma unroll
            for (int mt = 0; mt < 4; ++mt) {
                vv[mt][nt] = __builtin_amdgcn_mfma_f32_16x16x32_f16(ah[mt], gh, vv[mt][nt], 0, 0, 0);
                vv[mt][nt] = __builtin_amdgcn_mfma_f32_16x16x32_f16(ah[mt], gl, vv[mt][nt], 0, 0, 0);
                vv[mt][nt] = __builtin_amdgcn_mfma_f32_16x16x32_f16(al[mt], gh, vv[mt][nt], 0, 0, 0);
            }
        }
    }
    __syncthreads();   // sync #2: P visible to all waves

    // ---- phase O: O[all i][w's band] = P @ V^T. A = P (LDS), B = V via shfl
    f32x4 oc[4][4];
#pragma unroll
    for (int mt = 0; mt < 4; ++mt)
#pragma unroll
        for (int nt = 0; nt < 4; ++nt) oc[mt][nt] = (f32x4){0.f, 0.f, 0.f, 0.f};
#pragma unroll
    for (int kt = 0; kt < 2; ++kt) {
        half8 pah[4], pal[4];
#pragma unroll
        for (int mt = 0; mt < 4; ++mt) {
            int po = pswz(mt * 16 + l15, kt * 32 + lq * 8);
            pah[mt] = *(const half8*)(Phc + po);
            pal[mt] = *(const half8*)(Plc + po);
        }
#pragma unroll
        for (int nt = 0; nt < 4; ++nt) {
            half8 vbh, vbl;
            xfrag(vv[kt * 2][nt], vv[kt * 2 + 1][nt], srcA, lane, 1.0f, vbh, vbl);
#pragma unroll
            for (int mt = 0; mt < 4; ++mt) {
                oc[mt][nt] = __builtin_amdgcn_mfma_f32_16x16x32_f16(pah[mt], vbh, oc[mt][nt], 0, 0, 0);
                oc[mt][nt] = __builtin_amdgcn_mfma_f32_16x16x32_f16(pah[mt], vbl, oc[mt][nt], 0, 0, 0);
                oc[mt][nt] = __builtin_amdgcn_mfma_f32_16x16x32_f16(pal[mt], vbh, oc[mt][nt], 0, 0, 0);
            }
        }
    }

    // ---- epilogue: z_out = O + 0.1*x0; zf1 (column mean over all 64 rows, per-wave)
    float zfs[4] = {0.f, 0.f, 0.f, 0.f};
#pragma unroll
    for (int mt = 0; mt < 4; ++mt)
#pragma unroll
        for (int nt = 0; nt < 4; ++nt)
#pragma unroll
            for (int r = 0; r < 4; ++r) {
                int i = mt * 16 + lq * 4 + r;
                int c = w * 64 + nt * 16 + l15;
                int zo = zswz(i, c);
                float x0 = (float)(*(const half_t*)(Zhc + zo)) + (float)(*(const half_t*)(Zlc + zo));
                float z1 = oc[mt][nt][r] + 0.1f * x0;
                zb[(size_t)i * FF + c] = z1;
                zfs[nt] += z1;
            }
#pragma unroll
    for (int nt = 0; nt < 4; ++nt) {
        zfs[nt] += __shfl_xor(zfs[nt], 16);
        zfs[nt] += __shfl_xor(zfs[nt], 32);
    }
    if (lq == 0) {
#pragma unroll
        for (int nt = 0; nt < 4; ++nt)
            zf1[b * FF + w * 64 + nt * 16 + l15] = zfs[nt] * (1.f / 64.f);
    }
}

// ---------------------------------------------------------------------------
// Split-fp16 MFMA GEMM (memory path): C[M][768] = A[M][256] @ W[256][768]
__global__ __launch_bounds__(256) void gemm_split(const float* __restrict__ A,
                                                  const half_t* __restrict__ WTh,
                                                  const half_t* __restrict__ WTl,
                                                  float* __restrict__ C) {
    __shared__ float As[128][36];
    int bm = blockIdx.x / 6;
    int bn = blockIdx.x % 6;
    int tid = threadIdx.x;
    int w = tid >> 6;
    int lane = tid & 63;
    int wr = w >> 1, wc = w & 1;
    int l15 = lane & 15;
    int lq  = lane >> 4;

    f32x4 acc[4][4];
#pragma unroll
    for (int i = 0; i < 4; ++i)
#pragma unroll
        for (int j = 0; j < 4; ++j) acc[i][j] = (f32x4){0.f, 0.f, 0.f, 0.f};

    const float* Ablk = A + (size_t)bm * 128 * 256;
    int colbase = bn * 128 + wc * 64;

    int srow = tid >> 1;
    int sseg = (tid & 1) * 16;

    for (int k0 = 0; k0 < 256; k0 += 32) {
        __syncthreads();
        {
            const float* src = Ablk + (size_t)srow * 256 + k0 + sseg;
            f32x4 v0 = *(const f32x4*)(src);
            f32x4 v1 = *(const f32x4*)(src + 4);
            f32x4 v2 = *(const f32x4*)(src + 8);
            f32x4 v3 = *(const f32x4*)(src + 12);
            *(f32x4*)&As[srow][sseg]      = v0;
            *(f32x4*)&As[srow][sseg + 4]  = v1;
            *(f32x4*)&As[srow][sseg + 8]  = v2;
            *(f32x4*)&As[srow][sseg + 12] = v3;
        }
        __syncthreads();

        half8 bh[4], bl[4];
#pragma unroll
        for (int tj = 0; tj < 4; ++tj) {
            size_t off = (size_t)(colbase + tj * 16 + l15) * 256 + k0 + lq * 8;
            bh[tj] = *(const half8*)(WTh + off);
            bl[tj] = *(const half8*)(WTl + off);
        }

        half8 ah[4], al[4];
#pragma unroll
        for (int ti = 0; ti < 4; ++ti) {
            const float* ap = &As[wr * 64 + ti * 16 + l15][lq * 8];
            f32x4 a0 = *(const f32x4*)(ap);
            f32x4 a1 = *(const f32x4*)(ap + 4);
#pragma unroll
            for (int j = 0; j < 4; ++j) {
                float x = a0[j];
                half_t h = (half_t)x;
                ah[ti][j] = h;
                al[ti][j] = (half_t)(x - (float)h);
            }
#pragma unroll
            for (int j = 0; j < 4; ++j) {
                float x = a1[j];
                half_t h = (half_t)x;
                ah[ti][4 + j] = h;
                al[ti][4 + j] = (half_t)(x - (float)h);
            }
        }

#pragma unroll
        for (int ti = 0; ti < 4; ++ti)
#pragma unroll
            for (int tj = 0; tj < 4; ++tj)
                acc[ti][tj] = __builtin_amdgcn_mfma_f32_16x16x32_f16(ah[ti], bh[tj], acc[ti][tj], 0, 0, 0);
#pragma unroll
        for (int ti = 0; ti < 4; ++ti)
#pragma unroll
            for (int tj = 0; tj < 4; ++tj)
                acc[ti][tj] = __builtin_amdgcn_mfma_f32_16x16x32_f16(ah[ti], bl[tj], acc[ti][tj], 0, 0, 0);
#pragma unroll
        for (int ti = 0; ti < 4; ++ti)
#pragma unroll
            for (int tj = 0; tj < 4; ++tj)
                acc[ti][tj] = __builtin_amdgcn_mfma_f32_16x16x32_f16(al[ti], bh[tj], acc[ti][tj], 0, 0, 0);
    }

    float* Cb = C + (size_t)(bm * 128 + wr * 64) * 768 + bn * 128 + wc * 64;
#pragma unroll
    for (int ti = 0; ti < 4; ++ti)
#pragma unroll
        for (int tj = 0; tj < 4; ++tj) {
            int r0 = ti * 16 + lq * 4;
            int c0 = tj * 16 + l15;
#pragma unroll
            for (int r = 0; r < 4; ++r)
                Cb[(size_t)(r0 + r) * 768 + c0] = acc[ti][tj][r];
        }
}

// ---------------------------------------------------------------------------
__global__ __launch_bounds__(256) void k_gate(const float* __restrict__ zf1,
                                              const float* __restrict__ ctrl_w,
                                              const float* __restrict__ ctrl_b,
                                              float* __restrict__ ptrv,
                                              float* __restrict__ memv) {
    __shared__ float zf[256];
    __shared__ float g[3];
    __shared__ float oldp[16];
    int b = blockIdx.x, tid = threadIdx.x;
    zf[tid] = zf1[b * FF + tid];
    if (tid < 16) oldp[tid] = ptrv[b * STK + tid];
    __syncthreads();
    int w = tid >> 6, lane = tid & 63;
    if (w < 3) {
        float s = 0.f;
#pragma unroll
        for (int q = 0; q < 4; ++q) {
            int c = lane + 64 * q;
            s += zf[c] * ctrl_w[c * 3 + w];
        }
#pragma unroll
        for (int off = 1; off < 64; off <<= 1) s += __shfl_xor(s, off);
        if (lane == 0) g[w] = 1.f / (1.f + expf(-(s + ctrl_b[w])));
    }
    __syncthreads();
    float tot = g[0] + g[1] + g[2] + 1e-6f;
    float push = g[0] / tot, pop = g[1] / tot, stay = g[2] / tot;
    if (tid < 16) {
        int s = tid;
        float np = push * oldp[(s + 15) & 15] + pop * oldp[(s + 1) & 15] + stay * oldp[s];
        ptrv[b * STK + s] = np;
    }
    for (int idx = tid; idx < STK * FF; idx += 256) {
        int c = idx & 255;
        size_t gi = (size_t)b * (STK * FF) + idx;
        float m = memv[gi];
        memv[gi] = m * (1.f - push) + push * zf[c];
    }
}

// ---------------------------------------------------------------------------
__global__ __launch_bounds__(256) void k_memattn(const float* __restrict__ memqkv,
                                                 const float* __restrict__ ptrv,
                                                 float* __restrict__ readv) {
    __shared__ float mq[16][257];
    __shared__ float mk[16][257];
    __shared__ float mv[16][257];
    __shared__ float sm[16][17];
    __shared__ float rowmax[16], rowsum[16], pw[16];
    int b = blockIdx.x, tid = threadIdx.x;
    const float* mb = memqkv + (size_t)b * STK * 768;
    for (int idx = tid; idx < STK * FF; idx += 256) {
        int t = idx >> 8, c = idx & 255;
        mq[t][c] = mb[t * 768 + c];
        mk[t][c] = mb[t * 768 + 256 + c];
        mv[t][c] = mb[t * 768 + 512 + c];
    }
    __syncthreads();
    int i = tid >> 4, j = tid & 15;
    float s = 0.f;
#pragma unroll 8
    for (int c = 0; c < 256; ++c) s += mq[i][c] * mk[j][c];
    s *= 0.08838834764831845f;
    sm[i][j] = s;
    __syncthreads();
    if (tid < 16) {
        float m = -1e30f;
        for (int jj = 0; jj < 16; ++jj) m = fmaxf(m, sm[tid][jj]);
        float su = 0.f;
        for (int jj = 0; jj < 16; ++jj) su += expf(sm[tid][jj] - m);
        rowmax[tid] = m; rowsum[tid] = su;
    }
    __syncthreads();
    float p = expf(s - rowmax[i]) / rowsum[i];
    sm[i][j] = p;
    __syncthreads();
    if (tid < 16) {
        float a = 0.f;
        for (int ss2 = 0; ss2 < 16; ++ss2) a += ptrv[b * STK + ss2] * sm[ss2][tid];
        pw[tid] = a;
    }
    __syncthreads();
    {
        int c = tid;
        float a = 0.f;
#pragma unroll
        for (int jj = 0; jj < 16; ++jj) a += pw[jj] * mv[jj][c];
        readv[b * FF + c] = a;
    }
}

// ---------------------------------------------------------------------------
__device__ __forceinline__ float bredsum(float v, float* red, int n) {
    red[n] = v; __syncthreads();
    for (int off = 64; off > 0; off >>= 1) {
        if (n < off) red[n] += red[n + off];
        __syncthreads();
    }
    float r = red[0];
    __syncthreads();
    return r;
}
__device__ __forceinline__ float bredmax(float v, float* red, int n) {
    red[n] = v; __syncthreads();
    for (int off = 64; off > 0; off >>= 1) {
        if (n < off) red[n] = fmaxf(red[n], red[n + off]);
        __syncthreads();
    }
    float r = red[0];
    __syncthreads();
    return r;
}

// Read-only z sweep: mag partial sums; zf2 = zf1 + 0.1*read; halting logit.
__global__ __launch_bounds__(128) void k_mag(const float* __restrict__ z,
                                             const float* __restrict__ readv,
                                             const float* __restrict__ zf1,
                                             float* __restrict__ zf2,
                                             const float* __restrict__ halt_w,
                                             const float* __restrict__ halt_b,
                                             float* __restrict__ pval,
                                             float* __restrict__ magpart) {
    __shared__ float red[128];
    int b = blockIdx.x, d = threadIdx.x;
    float rr = 0.1f * readv[b * FF + d];
    float ri = 0.1f * readv[b * FF + DD + d];
    float ms = 0.f, msq = 0.f;
    const float* zb = z + (size_t)b * (SS * FF);
    for (int s = 0; s < SS; ++s) {
        float zr = zb[s * FF + d] + rr;
        float zi = zb[s * FF + DD + d] + ri;
        float m2 = zr * zr + zi * zi;
        ms += sqrtf(m2); msq += m2;
    }
    float zfr = zf1[b * FF + d] + rr;
    float zfi = zf1[b * FF + DD + d] + ri;
    zf2[b * FF + d] = zfr;
    zf2[b * FF + DD + d] = zfi;
    float tms = bredsum(ms, red, d);
    float tmsq = bredsum(msq, red, d);
    if (d == 0) { magpart[2 * b] = tms; magpart[2 * b + 1] = tmsq; }
    float hp = zfr * halt_w[d] + zfi * halt_w[DD + d];
    float thp = bredsum(hp, red, d);
    if (d == 0) pval[b] = 1.f / (1.f + expf(-(thp + halt_b[0])));
}

// VQ + ACT bookkeeping; writes delta = read + quant.
__global__ __launch_bounds__(128) void k_vq(const float* __restrict__ zf2,
                                            const float* __restrict__ cb,
                                            const float* __restrict__ cb2,
                                            const float* __restrict__ adj,
                                            float* __restrict__ probs,
                                            float* __restrict__ delta,
                                            const float* __restrict__ readv,
                                            float* __restrict__ halt,
                                            const float* __restrict__ pval,
                                            float* __restrict__ wact,
                                            const float* __restrict__ magpart, int t) {
    __shared__ float red[128];
    __shared__ float zf[256];
    __shared__ float pr[128];
    int b = blockIdx.x, n = threadIdx.x;
    zf[n] = zf2[b * FF + n];
    zf[DD + n] = zf2[b * FF + DD + n];
    float up = 0.f;
    if (t > 0) {
        float pa = 0.f, pb = 0.f;
        for (int k = n; k < BB; k += 128) { pa += magpart[2 * k]; pb += magpart[2 * k + 1]; }
        float tms = bredsum(pa, red, n);
        float tmsq = bredsum(pb, red, n);
        const float N = 4194304.f;   // B*S*D
        float mean = tms / N;
        float var = tmsq / N - mean * mean;
        float x = var / (1.f + 1e-6f);
        up = (x > 20.f) ? x : log1pf(expf(x));
    }
    __syncthreads();
    float part = zf[n] * zf[n] + zf[DD + n] * zf[DD + n];
    float zz = bredsum(part, red, n);
    float dot = 0.f;
    const float* cbn = cb + n * FF;
#pragma unroll 8
    for (int c = 0; c < FF; ++c) dot += zf[c] * cbn[c];
    float dist = (zz + cb2[n] - 2.f * dot) * (1.f / 256.f);
    float dtot = dist;
    if (t > 0) {
        float gb = 0.f;
        const float* pp = probs + b * NSYM;
        for (int k = 0; k < NSYM; ++k) gb += pp[k] * adj[k * NSYM + n];
        dtot = dist - 0.01f * up * (1.f / (1.f + expf(-gb)));
    }
    float v = -dtot;   // TEMP = 1
    float mx = bredmax(v, red, n);
    float e = expf(v - mx);
    float se = bredsum(e, red, n);
    float psm = e / se;
    pr[n] = psm;
    __syncthreads();
    probs[b * NSYM + n] = psm;
    float q0 = 0.f, q1 = 0.f;
    for (int k = 0; k < NSYM; ++k) {
        float pk = pr[k];
        q0 += pk * cb[k * FF + n];
        q1 += pk * cb[k * FF + DD + n];
    }
    delta[b * FF + n]      = readv[b * FF + n] + q0;
    delta[b * FF + DD + n] = readv[b * FF + DD + n] + q1;
    if (n == 0) {
        float h = halt[b], p = pval[b];
        float running = (h < 0.99f) ? 1.f : 0.f;
        float w = (((h + p * running) >= 0.99f) ? (1.f - h) : p) * running;
        halt[b] = h + w;
        wact[b] = w;
    }
}

// Final deferred quant/read + ACT accumulation.
__global__ __launch_bounds__(256) void k_epilogue(const float* __restrict__ z,
                                                  const float* __restrict__ delta,
                                                  const float* __restrict__ wact,
                                                  float* __restrict__ acc) {
    int idx = blockIdx.x * 256 + threadIdx.x;   // grid 32768 -> 8388608
    int b = idx >> 14;
    int c = idx & 255;
    float wa = wact[b];
    if (wa != 0.0f)
        acc[idx] += wa * (z[idx] + 0.1f * delta[b * FF + c]);
}

// ---------------------------------------------------------------------------
extern "C" void kernel_launch(void* const* d_in, const int* in_sizes, int n_in,
                              void* d_out, int out_size, void* d_ws, size_t ws_size,
                              hipStream_t stream) {
    const float* z_real  = (const float*)d_in[0];
    const float* z_imag  = (const float*)d_in[1];
    const float* attn_wr = (const float*)d_in[2];
    const float* attn_wi = (const float*)d_in[3];
    const float* mem_wr  = (const float*)d_in[4];
    const float* mem_wi  = (const float*)d_in[5];
    const float* ctrl_w  = (const float*)d_in[6];
    const float* ctrl_b  = (const float*)d_in[7];
    const float* halt_w  = (const float*)d_in[8];
    const float* halt_b  = (const float*)d_in[9];
    const float* codebook  = (const float*)d_in[10];
    const float* adjacency = (const float*)d_in[11];

    float* ws = (float*)d_ws;
    float* z      = ws + Z_OFF;
    float* WT32   = ws + QKV_OFF;
    half_t* GTh   = (half_t*)(ws + QKV_OFF + 196608);
    half_t* GTl   = GTh + 65536;
    half_t* WvTh  = GTl + 65536;
    half_t* WvTl  = WvTh + 65536;
    float* memv   = ws + MEM_OFF;
    float* memqkv = ws + MEMQKV_OFF;
    float* ptrv   = ws + PTR_OFF;
    float* zf1    = ws + ZF1_OFF;
    float* zf2    = ws + ZF2_OFF;
    float* readv  = ws + READ_OFF;
    float* probs  = ws + PROBS_OFF;
    float* delta  = ws + DELTA_OFF;
    float* halt   = ws + HALT_OFF;
    float* pval   = ws + PVAL_OFF;
    float* wact   = ws + WACT_OFF;
    float* magp   = ws + MAGP_OFF;
    half_t* WTh_m = (half_t*)(ws + MQKV_OFF);
    half_t* WTl_m = (half_t*)(ws + MQKV_OFF) + 196608;
    float* cb2    = ws + CB2_OFF;
    float* acc    = (float*)d_out;

    k_buildwt32<<<768, 256, 0, stream>>>(attn_wr, attn_wi, WT32);
    k_buildG<<<256, 256, 0, stream>>>(WT32, GTh, GTl);
    k_splitWv<<<256, 256, 0, stream>>>(WT32, WvTh, WvTl);
    k_buildwt<<<768, 256, 0, stream>>>(mem_wr, mem_wi, WTh_m, WTl_m);
    k_cb2<<<1, 128, 0, stream>>>(codebook, cb2);
    k_init<<<32768, 256, 0, stream>>>(z_real, z_imag, z, memv, ptrv, probs, halt, acc,
                                      delta, wact);

    for (int t = 0; t < NDEPTH; ++t) {
        k_attn2<<<BB, 256, 0, stream>>>(z, GTh, GTl, WvTh, WvTl, delta, wact, acc, zf1);
        k_gate<<<BB, 256, 0, stream>>>(zf1, ctrl_w, ctrl_b, ptrv, memv);
        gemm_split<<<(BB * STK / 128) * 6, 256, 0, stream>>>(memv, WTh_m, WTl_m, memqkv);
        k_memattn<<<BB, 256, 0, stream>>>(memqkv, ptrv, readv);
        k_mag<<<BB, 128, 0, stream>>>(z, readv, zf1, zf2, halt_w, halt_b, pval, magp);
        k_vq<<<BB, 128, 0, stream>>>(zf2, codebook, cb2, adjacency, probs, delta, readv,
                                     halt, pval, wact, magp, t);
    }
    k_epilogue<<<32768, 256, 0, stream>>>(z, delta, wact, acc);
}

// Round 6
// 1038.907 us; speedup vs baseline: 1.3092x; 1.3092x over previous
//
#include <hip/hip_runtime.h>
#include <math.h>

// Problem constants
#define BB 512
#define SS 64
#define DD 128
#define FF 256   // 2D
#define NSYM 128
#define STK 16
#define NDEPTH 8

typedef _Float16 half_t;
typedef __attribute__((ext_vector_type(4))) _Float16 half4;
typedef __attribute__((ext_vector_type(8))) _Float16 half8;
typedef __attribute__((ext_vector_type(4))) float f32x4;

// Workspace offsets (in floats)
#define Z_OFF      0ull                    // B*S*F      = 8388608
#define QKV_OFF    8388608ull              // WT32 + GT/WvT split planes
#define MEM_OFF    33554432ull             // B*16*F     = 2097152
#define MEMQKV_OFF 35651584ull             // B*16*768   = 6291456
#define PTR_OFF    41943040ull             // B*16       = 8192
#define ZF1_OFF    41951232ull             // B*256      = 131072
#define ZF2_OFF    42082304ull             // B*256      = 131072
#define READ_OFF   42213376ull             // B*256      = 131072
#define PROBS_OFF  42344448ull             // B*128      = 65536
#define DELTA_OFF  42409984ull             // B*256      = 131072 (read + quant)
#define HALT_OFF   42541056ull             // B          = 512
#define PVAL_OFF   42541568ull             // B          = 512
#define WACT_OFF   42542080ull             // B          = 512
#define MAGP_OFF   42542592ull             // B*2        = 1024
#define MQKV_OFF   42740224ull             // 196608 floats (MTh+MTl fp16)
#define CB2_OFF    42936832ull             // 128

// ---------------------------------------------------------------------------
// Combined transposed weight, fp32: WT32[h][c][e] = W_h[e][c], h in {q,k,v}
__global__ void k_buildwt32(const float* __restrict__ wr, const float* __restrict__ wi,
                            float* __restrict__ WT32) {
    int idx = blockIdx.x * 256 + threadIdx.x;   // 196608 total, grid=768
    if (idx >= 768 * 256) return;
    int col = idx >> 8;     // 0..767 = h*256 + c
    int e   = idx & 255;
    int h   = col >> 8;
    int c   = col & 255;
    const float* Wr = wr + h * DD * DD;
    const float* Wi = wi + h * DD * DD;
    float v;
    if (c < DD) {
        v = (e < DD) ? Wr[c * DD + e] : -Wi[c * DD + (e - DD)];
    } else {
        int j = c - DD;
        v = (e < DD) ? Wi[j * DD + e] : Wr[j * DD + (e - DD)];
    }
    WT32[idx] = v;
}

// GT[n][e] = G[e][n] = sum_c Wq[e][c]*Wk[n][c], split to fp16 h/l (unscaled).
__global__ __launch_bounds__(256) void k_buildG(const float* __restrict__ WT32,
                                                half_t* __restrict__ GTh,
                                                half_t* __restrict__ GTl) {
    __shared__ float kcol[256];
    int n = blockIdx.x;       // 0..255
    int e = threadIdx.x;      // 0..255
    kcol[e] = WT32[65536 + e * 256 + n];   // Wk[n][c=e]
    __syncthreads();
    float s = 0.f;
    for (int c = 0; c < 256; ++c) s += kcol[c] * WT32[c * 256 + e];  // Wq[e][c]
    half_t h = (half_t)s;
    GTh[n * 256 + e] = h;
    GTl[n * 256 + e] = (half_t)(s - (float)h);
}

__global__ void k_splitWv(const float* __restrict__ WT32,
                          half_t* __restrict__ WvTh, half_t* __restrict__ WvTl) {
    int idx = blockIdx.x * 256 + threadIdx.x;   // 65536, grid 256
    float v = WT32[131072 + idx];   // WvT[n][e] = Wv[e][n]
    half_t h = (half_t)v;
    WvTh[idx] = h;
    WvTl[idx] = (half_t)(v - (float)h);
}

// Memory-path combined transposed split weights.
__global__ void k_buildwt(const float* __restrict__ wr, const float* __restrict__ wi,
                          half_t* __restrict__ WTh, half_t* __restrict__ WTl) {
    int idx = blockIdx.x * 256 + threadIdx.x;   // 196608 total, grid=768
    if (idx >= 768 * 256) return;
    int col = idx >> 8;
    int e   = idx & 255;
    int h   = col >> 8;
    int c   = col & 255;
    const float* Wr = wr + h * DD * DD;
    const float* Wi = wi + h * DD * DD;
    float v;
    if (c < DD) {
        v = (e < DD) ? Wr[c * DD + e] : -Wi[c * DD + (e - DD)];
    } else {
        int j = c - DD;
        v = (e < DD) ? Wi[j * DD + e] : Wr[j * DD + (e - DD)];
    }
    half_t hh = (half_t)v;
    WTh[idx] = hh;
    WTl[idx] = (half_t)(v - (float)hh);
}

__global__ void k_cb2(const float* __restrict__ cb, float* __restrict__ cb2) {
    int n = threadIdx.x;   // 128 threads
    float s = 0.f;
    for (int c = 0; c < FF; ++c) { float v = cb[n * FF + c]; s += v * v; }
    cb2[n] = s;
}

__global__ __launch_bounds__(256) void k_init(const float* __restrict__ zr_in,
                                              const float* __restrict__ zi_in,
                                              float* __restrict__ z, float* __restrict__ memv,
                                              float* __restrict__ ptrv, float* __restrict__ probs,
                                              float* __restrict__ halt, float* __restrict__ acc,
                                              float* __restrict__ delta, float* __restrict__ wact) {
    size_t idx = (size_t)blockIdx.x * 256 + threadIdx.x;  // grid 32768 -> 8388608
    int c = (int)(idx & 255);
    size_t bs = idx >> 8;
    z[idx] = (c < DD) ? zr_in[bs * DD + c] : zi_in[bs * DD + (c - DD)];
    acc[idx] = 0.f;
    if (idx < 2097152) memv[idx] = 0.f;
    if (idx < 131072) delta[idx] = 0.f;
    if (idx < 8192)  ptrv[idx] = ((idx & 15) == 0) ? 1.f : 0.f;
    if (idx < 65536) probs[idx] = 0.f;
    if (idx < 512)   { halt[idx] = 0.f; wact[idx] = 0.f; }
}

// ---------------------------------------------------------------------------
// Fused attention step, 8 waves (512 thr), 1 block/CU, 2 waves/SIMD.
//   x0 = z + 0.1*delta_prev;  acc += wact_prev*x0
//   T = x0@G (scale folded) -> Ubuf;  waves 0-3: S^T = x0@T^T -> softmax -> P
//   every wave: V band = x0@Wv (regs);  VT -> Ubuf;  O = P@V^T (all waves)
//   z_out = O + 0.1*x0;  zf1 = colmean
__global__ __launch_bounds__(512, 1) void k_attn8(
        float* __restrict__ z,
        const half_t* __restrict__ GTh, const half_t* __restrict__ GTl,
        const half_t* __restrict__ WvTh, const half_t* __restrict__ WvTl,
        const float* __restrict__ delta, const float* __restrict__ wact,
        float* __restrict__ acc, float* __restrict__ zf1) {
    __shared__ half_t Zh[16896];         // 64 x 264 (stride-pad), 33 KB
    __shared__ half_t Zl[16896];         // 33 KB
    __shared__ half_t Ubuf[2][18432];    // union: T[64][264] / VT[256][72], 72 KB
    __shared__ half_t Pbuf[2][4][1152];  // P split, owner-wave x [16 q][72 j], 18 KB
    // total 159744 B

    int b = blockIdx.x, tid = threadIdx.x;
    int w = tid >> 6, lane = tid & 63;
    int l15 = lane & 15, lq = lane >> 4;
    float* zb = z + (size_t)b * (SS * FF);
    float* accb = acc + (size_t)b * (SS * FF);

    // ---- phase 0: x0 = z + 0.1*delta; deferred acc; split to LDS
    float wa = wact[b];
    f32x4 dv = *(const f32x4*)(delta + b * FF + lane * 4);
    bool doacc = (wa != 0.0f);
#pragma unroll
    for (int it = 0; it < 8; ++it) {
        int i = w * 8 + it;
        f32x4 zv = *(const f32x4*)(zb + (size_t)i * FF + lane * 4);
        f32x4 x0;
#pragma unroll
        for (int jj = 0; jj < 4; ++jj) x0[jj] = zv[jj] + 0.1f * dv[jj];
        if (doacc) {
            f32x4 av = *(const f32x4*)(accb + (size_t)i * FF + lane * 4);
#pragma unroll
            for (int jj = 0; jj < 4; ++jj) av[jj] += wa * x0[jj];
            *(f32x4*)(accb + (size_t)i * FF + lane * 4) = av;
        }
        half4 h4, l4;
#pragma unroll
        for (int jj = 0; jj < 4; ++jj) {
            half_t h = (half_t)x0[jj];
            h4[jj] = h; l4[jj] = (half_t)(x0[jj] - (float)h);
        }
        *(half4*)&Zh[i * 264 + lane * 4] = h4;
        *(half4*)&Zl[i * 264 + lane * 4] = l4;
    }
    __syncthreads();   // sync 1: Z staged

    // ---- phase T: T = x0 @ G, wave w owns 32-col band. A = x0 rows, B = GT band.
    {
        f32x4 tac[4][2];
#pragma unroll
        for (int mt = 0; mt < 4; ++mt)
#pragma unroll
            for (int nt = 0; nt < 2; ++nt) tac[mt][nt] = (f32x4){0.f, 0.f, 0.f, 0.f};
        for (int kt = 0; kt < 8; ++kt) {
            int kc = kt * 32 + lq * 8;
            half8 ah[4], al[4], gh[2], gl[2];
#pragma unroll
            for (int mt = 0; mt < 4; ++mt) {
                int ro = (mt * 16 + l15) * 264 + kc;
                ah[mt] = *(const half8*)&Zh[ro];
                al[mt] = *(const half8*)&Zl[ro];
            }
#pragma unroll
            for (int nt = 0; nt < 2; ++nt) {
                size_t go = (size_t)(w * 32 + nt * 16 + l15) * 256 + kc;
                gh[nt] = *(const half8*)(GTh + go);
                gl[nt] = *(const half8*)(GTl + go);
            }
#pragma unroll
            for (int mt = 0; mt < 4; ++mt)
#pragma unroll
                for (int nt = 0; nt < 2; ++nt) {
                    tac[mt][nt] = __builtin_amdgcn_mfma_f32_16x16x32_f16(ah[mt], gh[nt], tac[mt][nt], 0, 0, 0);
                    tac[mt][nt] = __builtin_amdgcn_mfma_f32_16x16x32_f16(ah[mt], gl[nt], tac[mt][nt], 0, 0, 0);
                    tac[mt][nt] = __builtin_amdgcn_mfma_f32_16x16x32_f16(al[mt], gh[nt], tac[mt][nt], 0, 0, 0);
                }
        }
        const float scale = 0.08838834764831845f;   // 128^-0.5 folded into T
#pragma unroll
        for (int mt = 0; mt < 4; ++mt)
#pragma unroll
            for (int nt = 0; nt < 2; ++nt)
#pragma unroll
                for (int r = 0; r < 4; ++r) {
                    int m = mt * 16 + lq * 4 + r;
                    int n = w * 32 + nt * 16 + l15;
                    float v = tac[mt][nt][r] * scale;
                    half_t h = (half_t)v;
                    Ubuf[0][m * 264 + n] = h;
                    Ubuf[1][m * 264 + n] = (half_t)(v - (float)h);
                }
    }
    __syncthreads();   // sync 2: T ready

    // ---- phase B: waves 0-3 compute S/softmax/P first; all waves then compute V band.
    if (w < 4) {
        f32x4 sac[4];
#pragma unroll
        for (int jt = 0; jt < 4; ++jt) sac[jt] = (f32x4){0.f, 0.f, 0.f, 0.f};
        for (int kt = 0; kt < 8; ++kt) {
            int kc = kt * 32 + lq * 8;
            int to = (w * 16 + l15) * 264 + kc;
            half8 bh = *(const half8*)&Ubuf[0][to];
            half8 bl = *(const half8*)&Ubuf[1][to];
            half8 ah[4], al[4];
#pragma unroll
            for (int jt = 0; jt < 4; ++jt) {
                int ro = (jt * 16 + l15) * 264 + kc;
                ah[jt] = *(const half8*)&Zh[ro];
                al[jt] = *(const half8*)&Zl[ro];
            }
#pragma unroll
            for (int jt = 0; jt < 4; ++jt) {
                sac[jt] = __builtin_amdgcn_mfma_f32_16x16x32_f16(ah[jt], bh, sac[jt], 0, 0, 0);
                sac[jt] = __builtin_amdgcn_mfma_f32_16x16x32_f16(ah[jt], bl, sac[jt], 0, 0, 0);
                sac[jt] = __builtin_amdgcn_mfma_f32_16x16x32_f16(al[jt], bh, sac[jt], 0, 0, 0);
            }
        }
        // softmax over j for query i = w*16+l15 (spread over lq group)
        float sv[4][4];
        float mx = -1e30f;
#pragma unroll
        for (int jt = 0; jt < 4; ++jt)
#pragma unroll
            for (int r = 0; r < 4; ++r) { sv[jt][r] = sac[jt][r]; mx = fmaxf(mx, sv[jt][r]); }
        mx = fmaxf(mx, __shfl_xor(mx, 16));
        mx = fmaxf(mx, __shfl_xor(mx, 32));
        float ssum = 0.f;
#pragma unroll
        for (int jt = 0; jt < 4; ++jt)
#pragma unroll
            for (int r = 0; r < 4; ++r) { float e = expf(sv[jt][r] - mx); sv[jt][r] = e; ssum += e; }
        ssum += __shfl_xor(ssum, 16);
        ssum += __shfl_xor(ssum, 32);
        float inv = 1.f / ssum;
#pragma unroll
        for (int jt = 0; jt < 4; ++jt) {
            half4 h4, l4;
#pragma unroll
            for (int r = 0; r < 4; ++r) {
                float pv = sv[jt][r] * inv;
                half_t hh = (half_t)pv;
                h4[r] = hh;
                l4[r] = (half_t)(pv - (float)hh);
            }
            *(half4*)&Pbuf[0][w][l15 * 72 + jt * 16 + lq * 4] = h4;
            *(half4*)&Pbuf[1][w][l15 * 72 + jt * 16 + lq * 4] = l4;
        }
    }

    // V band for this wave (cols [w*32, w*32+32)), result in regs
    f32x4 vac[4][2];
#pragma unroll
    for (int mt = 0; mt < 4; ++mt)
#pragma unroll
        for (int nt = 0; nt < 2; ++nt) vac[mt][nt] = (f32x4){0.f, 0.f, 0.f, 0.f};
    for (int kt = 0; kt < 8; ++kt) {
        int kc = kt * 32 + lq * 8;
        half8 ah[4], al[4], gh[2], gl[2];
#pragma unroll
        for (int mt = 0; mt < 4; ++mt) {
            int ro = (mt * 16 + l15) * 264 + kc;
            ah[mt] = *(const half8*)&Zh[ro];
            al[mt] = *(const half8*)&Zl[ro];
        }
#pragma unroll
        for (int nt = 0; nt < 2; ++nt) {
            size_t go = (size_t)(w * 32 + nt * 16 + l15) * 256 + kc;
            gh[nt] = *(const half8*)(WvTh + go);
            gl[nt] = *(const half8*)(WvTl + go);
        }
#pragma unroll
        for (int mt = 0; mt < 4; ++mt)
#pragma unroll
            for (int nt = 0; nt < 2; ++nt) {
                vac[mt][nt] = __builtin_amdgcn_mfma_f32_16x16x32_f16(ah[mt], gh[nt], vac[mt][nt], 0, 0, 0);
                vac[mt][nt] = __builtin_amdgcn_mfma_f32_16x16x32_f16(ah[mt], gl[nt], vac[mt][nt], 0, 0, 0);
                vac[mt][nt] = __builtin_amdgcn_mfma_f32_16x16x32_f16(al[mt], gh[nt], vac[mt][nt], 0, 0, 0);
            }
    }
    __syncthreads();   // sync 3: T reads done (S complete), V regs ready

    // VT write: VT[n][m] = V[m][n], stride 72
#pragma unroll
    for (int mt = 0; mt < 4; ++mt)
#pragma unroll
        for (int nt = 0; nt < 2; ++nt) {
            int n = w * 32 + nt * 16 + l15;
            int m0 = mt * 16 + lq * 4;
            half4 h4, l4;
#pragma unroll
            for (int r = 0; r < 4; ++r) {
                float v = vac[mt][nt][r];
                half_t h = (half_t)v;
                h4[r] = h; l4[r] = (half_t)(v - (float)h);
            }
            *(half4*)&Ubuf[0][n * 72 + m0] = h4;
            *(half4*)&Ubuf[1][n * 72 + m0] = l4;
        }
    __syncthreads();   // sync 4: VT + P visible

    // ---- phase O: O[all i][w's 32-col band] = P @ V^T
    f32x4 oc[4][2];
#pragma unroll
    for (int mt = 0; mt < 4; ++mt)
#pragma unroll
        for (int nt = 0; nt < 2; ++nt) oc[mt][nt] = (f32x4){0.f, 0.f, 0.f, 0.f};
#pragma unroll
    for (int kt = 0; kt < 2; ++kt) {
        half8 pah[4], pal[4];
#pragma unroll
        for (int mt = 0; mt < 4; ++mt) {
            int po = l15 * 72 + kt * 32 + lq * 8;
            pah[mt] = *(const half8*)&Pbuf[0][mt][po];
            pal[mt] = *(const half8*)&Pbuf[1][mt][po];
        }
#pragma unroll
        for (int nt = 0; nt < 2; ++nt) {
            int n = w * 32 + nt * 16 + l15;
            half8 vbh = *(const half8*)&Ubuf[0][n * 72 + kt * 32 + lq * 8];
            half8 vbl = *(const half8*)&Ubuf[1][n * 72 + kt * 32 + lq * 8];
#pragma unroll
            for (int mt = 0; mt < 4; ++mt) {
                oc[mt][nt] = __builtin_amdgcn_mfma_f32_16x16x32_f16(pah[mt], vbh, oc[mt][nt], 0, 0, 0);
                oc[mt][nt] = __builtin_amdgcn_mfma_f32_16x16x32_f16(pah[mt], vbl, oc[mt][nt], 0, 0, 0);
                oc[mt][nt] = __builtin_amdgcn_mfma_f32_16x16x32_f16(pal[mt], vbh, oc[mt][nt], 0, 0, 0);
            }
        }
    }

    // ---- epilogue: z_out = O + 0.1*x0; zf1 column means for this wave's band
    float zfs[2] = {0.f, 0.f};
#pragma unroll
    for (int mt = 0; mt < 4; ++mt)
#pragma unroll
        for (int nt = 0; nt < 2; ++nt)
#pragma unroll
            for (int r = 0; r < 4; ++r) {
                int i = mt * 16 + lq * 4 + r;
                int c = w * 32 + nt * 16 + l15;
                int zo = i * 264 + c;
                float x0 = (float)Zh[zo] + (float)Zl[zo];
                float z1 = oc[mt][nt][r] + 0.1f * x0;
                zb[(size_t)i * FF + c] = z1;
                zfs[nt] += z1;
            }
#pragma unroll
    for (int nt = 0; nt < 2; ++nt) {
        zfs[nt] += __shfl_xor(zfs[nt], 16);
        zfs[nt] += __shfl_xor(zfs[nt], 32);
    }
    if (lq == 0) {
#pragma unroll
        for (int nt = 0; nt < 2; ++nt)
            zf1[b * FF + w * 32 + nt * 16 + l15] = zfs[nt] * (1.f / 64.f);
    }
}

// ---------------------------------------------------------------------------
// Split-fp16 MFMA GEMM (memory path): C[M][768] = A[M][256] @ W[256][768]
__global__ __launch_bounds__(256) void gemm_split(const float* __restrict__ A,
                                                  const half_t* __restrict__ WTh,
                                                  const half_t* __restrict__ WTl,
                                                  float* __restrict__ C) {
    __shared__ float As[128][36];
    int bm = blockIdx.x / 6;
    int bn = blockIdx.x % 6;
    int tid = threadIdx.x;
    int w = tid >> 6;
    int lane = tid & 63;
    int wr = w >> 1, wc = w & 1;
    int l15 = lane & 15;
    int lq  = lane >> 4;

    f32x4 acc[4][4];
#pragma unroll
    for (int i = 0; i < 4; ++i)
#pragma unroll
        for (int j = 0; j < 4; ++j) acc[i][j] = (f32x4){0.f, 0.f, 0.f, 0.f};

    const float* Ablk = A + (size_t)bm * 128 * 256;
    int colbase = bn * 128 + wc * 64;

    int srow = tid >> 1;
    int sseg = (tid & 1) * 16;

    for (int k0 = 0; k0 < 256; k0 += 32) {
        __syncthreads();
        {
            const float* src = Ablk + (size_t)srow * 256 + k0 + sseg;
            f32x4 v0 = *(const f32x4*)(src);
            f32x4 v1 = *(const f32x4*)(src + 4);
            f32x4 v2 = *(const f32x4*)(src + 8);
            f32x4 v3 = *(const f32x4*)(src + 12);
            *(f32x4*)&As[srow][sseg]      = v0;
            *(f32x4*)&As[srow][sseg + 4]  = v1;
            *(f32x4*)&As[srow][sseg + 8]  = v2;
            *(f32x4*)&As[srow][sseg + 12] = v3;
        }
        __syncthreads();

        half8 bh[4], bl[4];
#pragma unroll
        for (int tj = 0; tj < 4; ++tj) {
            size_t off = (size_t)(colbase + tj * 16 + l15) * 256 + k0 + lq * 8;
            bh[tj] = *(const half8*)(WTh + off);
            bl[tj] = *(const half8*)(WTl + off);
        }

        half8 ah[4], al[4];
#pragma unroll
        for (int ti = 0; ti < 4; ++ti) {
            const float* ap = &As[wr * 64 + ti * 16 + l15][lq * 8];
            f32x4 a0 = *(const f32x4*)(ap);
            f32x4 a1 = *(const f32x4*)(ap + 4);
#pragma unroll
            for (int j = 0; j < 4; ++j) {
                float x = a0[j];
                half_t h = (half_t)x;
                ah[ti][j] = h;
                al[ti][j] = (half_t)(x - (float)h);
            }
#pragma unroll
            for (int j = 0; j < 4; ++j) {
                float x = a1[j];
                half_t h = (half_t)x;
                ah[ti][4 + j] = h;
                al[ti][4 + j] = (half_t)(x - (float)h);
            }
        }

#pragma unroll
        for (int ti = 0; ti < 4; ++ti)
#pragma unroll
            for (int tj = 0; tj < 4; ++tj)
                acc[ti][tj] = __builtin_amdgcn_mfma_f32_16x16x32_f16(ah[ti], bh[tj], acc[ti][tj], 0, 0, 0);
#pragma unroll
        for (int ti = 0; ti < 4; ++ti)
#pragma unroll
            for (int tj = 0; tj < 4; ++tj)
                acc[ti][tj] = __builtin_amdgcn_mfma_f32_16x16x32_f16(ah[ti], bl[tj], acc[ti][tj], 0, 0, 0);
#pragma unroll
        for (int ti = 0; ti < 4; ++ti)
#pragma unroll
            for (int tj = 0; tj < 4; ++tj)
                acc[ti][tj] = __builtin_amdgcn_mfma_f32_16x16x32_f16(al[ti], bh[tj], acc[ti][tj], 0, 0, 0);
    }

    float* Cb = C + (size_t)(bm * 128 + wr * 64) * 768 + bn * 128 + wc * 64;
#pragma unroll
    for (int ti = 0; ti < 4; ++ti)
#pragma unroll
        for (int tj = 0; tj < 4; ++tj) {
            int r0 = ti * 16 + lq * 4;
            int c0 = tj * 16 + l15;
#pragma unroll
            for (int r = 0; r < 4; ++r)
                Cb[(size_t)(r0 + r) * 768 + c0] = acc[ti][tj][r];
        }
}

// ---------------------------------------------------------------------------
__global__ __launch_bounds__(256) void k_gate(const float* __restrict__ zf1,
                                              const float* __restrict__ ctrl_w,
                                              const float* __restrict__ ctrl_b,
                                              float* __restrict__ ptrv,
                                              float* __restrict__ memv) {
    __shared__ float zf[256];
    __shared__ float g[3];
    __shared__ float oldp[16];
    int b = blockIdx.x, tid = threadIdx.x;
    zf[tid] = zf1[b * FF + tid];
    if (tid < 16) oldp[tid] = ptrv[b * STK + tid];
    __syncthreads();
    int w = tid >> 6, lane = tid & 63;
    if (w < 3) {
        float s = 0.f;
#pragma unroll
        for (int q = 0; q < 4; ++q) {
            int c = lane + 64 * q;
            s += zf[c] * ctrl_w[c * 3 + w];
        }
#pragma unroll
        for (int off = 1; off < 64; off <<= 1) s += __shfl_xor(s, off);
        if (lane == 0) g[w] = 1.f / (1.f + expf(-(s + ctrl_b[w])));
    }
    __syncthreads();
    float tot = g[0] + g[1] + g[2] + 1e-6f;
    float push = g[0] / tot, pop = g[1] / tot, stay = g[2] / tot;
    if (tid < 16) {
        int s = tid;
        float np = push * oldp[(s + 15) & 15] + pop * oldp[(s + 1) & 15] + stay * oldp[s];
        ptrv[b * STK + s] = np;
    }
    for (int idx = tid; idx < STK * FF; idx += 256) {
        int c = idx & 255;
        size_t gi = (size_t)b * (STK * FF) + idx;
        float m = memv[gi];
        memv[gi] = m * (1.f - push) + push * zf[c];
    }
}

// ---------------------------------------------------------------------------
__global__ __launch_bounds__(256) void k_memattn(const float* __restrict__ memqkv,
                                                 const float* __restrict__ ptrv,
                                                 float* __restrict__ readv) {
    __shared__ float mq[16][257];
    __shared__ float mk[16][257];
    __shared__ float mv[16][257];
    __shared__ float sm[16][17];
    __shared__ float rowmax[16], rowsum[16], pw[16];
    int b = blockIdx.x, tid = threadIdx.x;
    const float* mb = memqkv + (size_t)b * STK * 768;
    for (int idx = tid; idx < STK * FF; idx += 256) {
        int t = idx >> 8, c = idx & 255;
        mq[t][c] = mb[t * 768 + c];
        mk[t][c] = mb[t * 768 + 256 + c];
        mv[t][c] = mb[t * 768 + 512 + c];
    }
    __syncthreads();
    int i = tid >> 4, j = tid & 15;
    float s = 0.f;
#pragma unroll 8
    for (int c = 0; c < 256; ++c) s += mq[i][c] * mk[j][c];
    s *= 0.08838834764831845f;
    sm[i][j] = s;
    __syncthreads();
    if (tid < 16) {
        float m = -1e30f;
        for (int jj = 0; jj < 16; ++jj) m = fmaxf(m, sm[tid][jj]);
        float su = 0.f;
        for (int jj = 0; jj < 16; ++jj) su += expf(sm[tid][jj] - m);
        rowmax[tid] = m; rowsum[tid] = su;
    }
    __syncthreads();
    float p = expf(s - rowmax[i]) / rowsum[i];
    sm[i][j] = p;
    __syncthreads();
    if (tid < 16) {
        float a = 0.f;
        for (int ss2 = 0; ss2 < 16; ++ss2) a += ptrv[b * STK + ss2] * sm[ss2][tid];
        pw[tid] = a;
    }
    __syncthreads();
    {
        int c = tid;
        float a = 0.f;
#pragma unroll
        for (int jj = 0; jj < 16; ++jj) a += pw[jj] * mv[jj][c];
        readv[b * FF + c] = a;
    }
}

// ---------------------------------------------------------------------------
__device__ __forceinline__ float bredsum(float v, float* red, int n) {
    red[n] = v; __syncthreads();
    for (int off = 64; off > 0; off >>= 1) {
        if (n < off) red[n] += red[n + off];
        __syncthreads();
    }
    float r = red[0];
    __syncthreads();
    return r;
}
__device__ __forceinline__ float bredmax(float v, float* red, int n) {
    red[n] = v; __syncthreads();
    for (int off = 64; off > 0; off >>= 1) {
        if (n < off) red[n] = fmaxf(red[n], red[n + off]);
        __syncthreads();
    }
    float r = red[0];
    __syncthreads();
    return r;
}

// Read-only z sweep: mag partial sums; zf2 = zf1 + 0.1*read; halting logit.
__global__ __launch_bounds__(128) void k_mag(const float* __restrict__ z,
                                             const float* __restrict__ readv,
                                             const float* __restrict__ zf1,
                                             float* __restrict__ zf2,
                                             const float* __restrict__ halt_w,
                                             const float* __restrict__ halt_b,
                                             float* __restrict__ pval,
                                             float* __restrict__ magpart) {
    __shared__ float red[128];
    int b = blockIdx.x, d = threadIdx.x;
    float rr = 0.1f * readv[b * FF + d];
    float ri = 0.1f * readv[b * FF + DD + d];
    float ms = 0.f, msq = 0.f;
    const float* zb = z + (size_t)b * (SS * FF);
    for (int s = 0; s < SS; ++s) {
        float zr = zb[s * FF + d] + rr;
        float zi = zb[s * FF + DD + d] + ri;
        float m2 = zr * zr + zi * zi;
        ms += sqrtf(m2); msq += m2;
    }
    float zfr = zf1[b * FF + d] + rr;
    float zfi = zf1[b * FF + DD + d] + ri;
    zf2[b * FF + d] = zfr;
    zf2[b * FF + DD + d] = zfi;
    float tms = bredsum(ms, red, d);
    float tmsq = bredsum(msq, red, d);
    if (d == 0) { magpart[2 * b] = tms; magpart[2 * b + 1] = tmsq; }
    float hp = zfr * halt_w[d] + zfi * halt_w[DD + d];
    float thp = bredsum(hp, red, d);
    if (d == 0) pval[b] = 1.f / (1.f + expf(-(thp + halt_b[0])));
}

// VQ + ACT bookkeeping; writes delta = read + quant.
__global__ __launch_bounds__(128) void k_vq(const float* __restrict__ zf2,
                                            const float* __restrict__ cb,
                                            const float* __restrict__ cb2,
                                            const float* __restrict__ adj,
                                            float* __restrict__ probs,
                                            float* __restrict__ delta,
                                            const float* __restrict__ readv,
                                            float* __restrict__ halt,
                                            const float* __restrict__ pval,
                                            float* __restrict__ wact,
                                            const float* __restrict__ magpart, int t) {
    __shared__ float red[128];
    __shared__ float zf[256];
    __shared__ float pr[128];
    int b = blockIdx.x, n = threadIdx.x;
    zf[n] = zf2[b * FF + n];
    zf[DD + n] = zf2[b * FF + DD + n];
    float up = 0.f;
    if (t > 0) {
        float pa = 0.f, pb = 0.f;
        for (int k = n; k < BB; k += 128) { pa += magpart[2 * k]; pb += magpart[2 * k + 1]; }
        float tms = bredsum(pa, red, n);
        float tmsq = bredsum(pb, red, n);
        const float N = 4194304.f;   // B*S*D
        float mean = tms / N;
        float var = tmsq / N - mean * mean;
        float x = var / (1.f + 1e-6f);
        up = (x > 20.f) ? x : log1pf(expf(x));
    }
    __syncthreads();
    float part = zf[n] * zf[n] + zf[DD + n] * zf[DD + n];
    float zz = bredsum(part, red, n);
    float dot = 0.f;
    const float* cbn = cb + n * FF;
#pragma unroll 8
    for (int c = 0; c < FF; ++c) dot += zf[c] * cbn[c];
    float dist = (zz + cb2[n] - 2.f * dot) * (1.f / 256.f);
    float dtot = dist;
    if (t > 0) {
        float gb = 0.f;
        const float* pp = probs + b * NSYM;
        for (int k = 0; k < NSYM; ++k) gb += pp[k] * adj[k * NSYM + n];
        dtot = dist - 0.01f * up * (1.f / (1.f + expf(-gb)));
    }
    float v = -dtot;   // TEMP = 1
    float mx = bredmax(v, red, n);
    float e = expf(v - mx);
    float se = bredsum(e, red, n);
    float psm = e / se;
    pr[n] = psm;
    __syncthreads();
    probs[b * NSYM + n] = psm;
    float q0 = 0.f, q1 = 0.f;
    for (int k = 0; k < NSYM; ++k) {
        float pk = pr[k];
        q0 += pk * cb[k * FF + n];
        q1 += pk * cb[k * FF + DD + n];
    }
    delta[b * FF + n]      = readv[b * FF + n] + q0;
    delta[b * FF + DD + n] = readv[b * FF + DD + n] + q1;
    if (n == 0) {
        float h = halt[b], p = pval[b];
        float running = (h < 0.99f) ? 1.f : 0.f;
        float w = (((h + p * running) >= 0.99f) ? (1.f - h) : p) * running;
        halt[b] = h + w;
        wact[b] = w;
    }
}

// Final deferred quant/read + ACT accumulation.
__global__ __launch_bounds__(256) void k_epilogue(const float* __restrict__ z,
                                                  const float* __restrict__ delta,
                                                  const float* __restrict__ wact,
                                                  float* __restrict__ acc) {
    int idx = blockIdx.x * 256 + threadIdx.x;   // grid 32768 -> 8388608
    int b = idx >> 14;
    int c = idx & 255;
    float wa = wact[b];
    if (wa != 0.0f)
        acc[idx] += wa * (z[idx] + 0.1f * delta[b * FF + c]);
}

// ---------------------------------------------------------------------------
extern "C" void kernel_launch(void* const* d_in, const int* in_sizes, int n_in,
                              void* d_out, int out_size, void* d_ws, size_t ws_size,
                              hipStream_t stream) {
    const float* z_real  = (const float*)d_in[0];
    const float* z_imag  = (const float*)d_in[1];
    const float* attn_wr = (const float*)d_in[2];
    const float* attn_wi = (const float*)d_in[3];
    const float* mem_wr  = (const float*)d_in[4];
    const float* mem_wi  = (const float*)d_in[5];
    const float* ctrl_w  = (const float*)d_in[6];
    const float* ctrl_b  = (const float*)d_in[7];
    const float* halt_w  = (const float*)d_in[8];
    const float* halt_b  = (const float*)d_in[9];
    const float* codebook  = (const float*)d_in[10];
    const float* adjacency = (const float*)d_in[11];

    float* ws = (float*)d_ws;
    float* z      = ws + Z_OFF;
    float* WT32   = ws + QKV_OFF;
    half_t* GTh   = (half_t*)(ws + QKV_OFF + 196608);
    half_t* GTl   = GTh + 65536;
    half_t* WvTh  = GTl + 65536;
    half_t* WvTl  = WvTh + 65536;
    float* memv   = ws + MEM_OFF;
    float* memqkv = ws + MEMQKV_OFF;
    float* ptrv   = ws + PTR_OFF;
    float* zf1    = ws + ZF1_OFF;
    float* zf2    = ws + ZF2_OFF;
    float* readv  = ws + READ_OFF;
    float* probs  = ws + PROBS_OFF;
    float* delta  = ws + DELTA_OFF;
    float* halt   = ws + HALT_OFF;
    float* pval   = ws + PVAL_OFF;
    float* wact   = ws + WACT_OFF;
    float* magp   = ws + MAGP_OFF;
    half_t* WTh_m = (half_t*)(ws + MQKV_OFF);
    half_t* WTl_m = (half_t*)(ws + MQKV_OFF) + 196608;
    float* cb2    = ws + CB2_OFF;
    float* acc    = (float*)d_out;

    k_buildwt32<<<768, 256, 0, stream>>>(attn_wr, attn_wi, WT32);
    k_buildG<<<256, 256, 0, stream>>>(WT32, GTh, GTl);
    k_splitWv<<<256, 256, 0, stream>>>(WT32, WvTh, WvTl);
    k_buildwt<<<768, 256, 0, stream>>>(mem_wr, mem_wi, WTh_m, WTl_m);
    k_cb2<<<1, 128, 0, stream>>>(codebook, cb2);
    k_init<<<32768, 256, 0, stream>>>(z_real, z_imag, z, memv, ptrv, probs, halt, acc,
                                      delta, wact);

    for (int t = 0; t < NDEPTH; ++t) {
        k_attn8<<<BB, 512, 0, stream>>>(z, GTh, GTl, WvTh, WvTl, delta, wact, acc, zf1);
        k_gate<<<BB, 256, 0, stream>>>(zf1, ctrl_w, ctrl_b, ptrv, memv);
        gemm_split<<<(BB * STK / 128) * 6, 256, 0, stream>>>(memv, WTh_m, WTl_m, memqkv);
        k_memattn<<<BB, 256, 0, stream>>>(memqkv, ptrv, readv);
        k_mag<<<BB, 128, 0, stream>>>(z, readv, zf1, zf2, halt_w, halt_b, pval, magp);
        k_vq<<<BB, 128, 0, stream>>>(zf2, codebook, cb2, adjacency, probs, delta, readv,
                                     halt, pval, wact, magp, t);
    }
    k_epilogue<<<32768, 256, 0, stream>>>(z, delta, wact, acc);
}